// Round 10
// baseline (325.093 us; speedup 1.0000x reference)
//
#include <hip/hip_runtime.h>
#include <hip/hip_bf16.h>
#include <math.h>

#define BB 4096
#define DD 256
#define GG 100
#define GAMMA_C 0.8f
#define RHO_C 8.0f
#define ALPHA_C 0.5f
#define EPS_C 1e-14f
#define NSR 64    // row stripes (64-col tiles)
#define NSC 128   // col stripes (32-row wave stripes)

typedef __bf16 bf16x8 __attribute__((ext_vector_type(8)));
typedef float f32x16 __attribute__((ext_vector_type(16)));

// 32-row fragment-swizzled layout for mfma_32x32x16: element (r,k) ->
//   row_blk=r>>5 (stride 8192), step=k>>4 (stride 512),
//   lane=((k>>3)&1)*32 + (r&31) (stride 8), pos=k&7. Packs exactly.
__device__ inline int swzLoc(int r31, int k) {   // offset within 8192-elem block
    return ((k >> 4) << 9) | (((((k >> 3) & 1) << 5) | r31) << 3) | (k & 7);
}

__device__ inline float blockReduceSum(float v, float* lds) {
    for (int o = 32; o > 0; o >>= 1) v += __shfl_down(v, o);
    int lane = threadIdx.x & 63, wid = threadIdx.x >> 6;
    if (lane == 0) lds[wid] = v;
    __syncthreads();
    if (threadIdx.x == 0) {
        float r = lds[0];
        int nw = blockDim.x >> 6;
        for (int w = 1; w < nw; w++) r += lds[w];
        lds[0] = r;
    }
    __syncthreads();
    float r = lds[0];
    __syncthreads();
    return r;
}

// ---------------- 1) normalize + hi/lo split, LDS-staged swizzled stores ----
// One block per 32-row swizzle super-block; stage swizzled layout in LDS,
// then fully-coalesced uint4 copy-out (fixes R7-R9 scattered 2B stores).
__global__ void __launch_bounds__(256) norm_kernel(const float* __restrict__ zis,
                            const float* __restrict__ zjs,
                            ushort* __restrict__ zhi, ushort* __restrict__ zlo,
                            ushort* __restrict__ whi, ushort* __restrict__ wlo,
                            float* __restrict__ diag, float* __restrict__ acc) {
    __shared__ ushort st[4][8192];   // 64 KB staging (zhi,zlo,whi,wlo)
    int rb = blockIdx.x;             // 0..127
    int wv = threadIdx.x >> 6, lane = threadIdx.x & 63;
    if (rb == 0) { acc[threadIdx.x] = 0.f; acc[threadIdx.x + 256] = 0.f; }
    for (int rr = 0; rr < 8; rr++) {
        int r = rb * 32 + wv * 8 + rr;
        float4 zv = *(const float4*)&zis[r * DD + lane * 4];
        float4 wv4 = *(const float4*)&zjs[r * DD + lane * 4];
        float sz = zv.x * zv.x + zv.y * zv.y + zv.z * zv.z + zv.w * zv.w;
        float sw = wv4.x * wv4.x + wv4.y * wv4.y + wv4.z * wv4.z + wv4.w * wv4.w;
        float dt = zv.x * wv4.x + zv.y * wv4.y + zv.z * wv4.z + zv.w * wv4.w;
        for (int mask = 1; mask <= 32; mask <<= 1) {
            sz += __shfl_xor(sz, mask);
            sw += __shfl_xor(sw, mask);
            dt += __shfl_xor(dt, mask);
        }
        float iz = 1.0f / fmaxf(sqrtf(sz), 1e-12f);
        float iw = 1.0f / fmaxf(sqrtf(sw), 1e-12f);
        if (lane == 0) diag[r] = dt * iz * iw;
        float nz[4] = {zv.x * iz, zv.y * iz, zv.z * iz, zv.w * iz};
        float nw[4] = {wv4.x * iw, wv4.y * iw, wv4.z * iw, wv4.w * iw};
        int r31 = wv * 8 + rr;
        for (int e = 0; e < 4; e++) {
            int k = lane * 4 + e;
            int li = swzLoc(r31, k);
            __hip_bfloat16 hz = __float2bfloat16(nz[e]);
            __hip_bfloat16 lz = __float2bfloat16(nz[e] - __bfloat162float(hz));
            __hip_bfloat16 hw = __float2bfloat16(nw[e]);
            __hip_bfloat16 lw = __float2bfloat16(nw[e] - __bfloat162float(hw));
            st[0][li] = *(ushort*)&hz;
            st[1][li] = *(ushort*)&lz;
            st[2][li] = *(ushort*)&hw;
            st[3][li] = *(ushort*)&lw;
        }
    }
    __syncthreads();
    size_t base = (size_t)rb * 8192;
    ushort* dsts[4] = {zhi + base, zlo + base, whi + base, wlo + base};
    for (int a = 0; a < 4; a++) {
        uint4* d = (uint4*)dsts[a];
        const uint4* s = (const uint4*)st[a];
        for (int it = 0; it < 4; it++) {
            int idx = it * 256 + threadIdx.x;
            d[idx] = s[idx];
        }
    }
}

// ---------------- 2) fused tile: 128x64 block, 32x32x16 MFMA, prefetched ----
// Per wave: 32 rows x 64 cols -> acc = 2x 16-reg (32 AGPR). Per K-step 6
// fragments (24 VGPR); cur+next double-buffer + addr + acc ~ 110 combined
// <= 128 -> compiler can pipeline a full step ahead (R9's 64+64 could not).
__global__ void __launch_bounds__(256, 4) fused_tile(const ushort* __restrict__ Ahi,
        const ushort* __restrict__ Alo, const ushort* __restrict__ Bhi,
        const ushort* __restrict__ Blo, const float* __restrict__ diag,
        const float* __restrict__ tausI, const float* __restrict__ tausT,
        const int* __restrict__ ids,
        float* __restrict__ pmR, float* __restrict__ pgR, float* __restrict__ pwR,
        float* __restrict__ pmC, float* __restrict__ pgC, float* __restrict__ pwC) {
    __shared__ float rDiag[128], rITau[128];
    __shared__ float cDiag[64], cITau[64];

    int lane = threadIdx.x & 63;
    int wv = threadIdx.x >> 6;
    int bm = blockIdx.y * 128, bn = blockIdx.x * 64;
    int h = lane >> 5, cl = lane & 31;

    if (threadIdx.x < 128) {
        int r = bm + threadIdx.x;
        rDiag[threadIdx.x] = diag[r];
        rITau[threadIdx.x] = 1.0f / tausI[ids[r]];
    } else if (threadIdx.x < 192) {
        int c = bn + threadIdx.x - 128;
        cDiag[threadIdx.x - 128] = diag[c];
        cITau[threadIdx.x - 128] = 1.0f / tausT[ids[c]];
    }

    int aBase = (blockIdx.y * 4 + wv) * 8192;
    int b0 = (blockIdx.x * 2) * 8192;
    int b1 = b0 + 8192;
    int lofs = lane * 8;

    f32x16 acc[2] = {};
    bf16x8 ah, al, bh0, bl0, bh1, bl1;
    ah  = *(const bf16x8*)&Ahi[aBase + lofs];
    al  = *(const bf16x8*)&Alo[aBase + lofs];
    bh0 = *(const bf16x8*)&Bhi[b0 + lofs];
    bl0 = *(const bf16x8*)&Blo[b0 + lofs];
    bh1 = *(const bf16x8*)&Bhi[b1 + lofs];
    bl1 = *(const bf16x8*)&Blo[b1 + lofs];
#pragma unroll
    for (int s = 0; s < 16; s++) {
        bf16x8 nah, nal, nbh0, nbl0, nbh1, nbl1;
        if (s < 15) {
            int so = (s + 1) * 512 + lofs;
            nah  = *(const bf16x8*)&Ahi[aBase + so];
            nal  = *(const bf16x8*)&Alo[aBase + so];
            nbh0 = *(const bf16x8*)&Bhi[b0 + so];
            nbl0 = *(const bf16x8*)&Blo[b0 + so];
            nbh1 = *(const bf16x8*)&Bhi[b1 + so];
            nbl1 = *(const bf16x8*)&Blo[b1 + so];
        }
        acc[0] = __builtin_amdgcn_mfma_f32_32x32x16_bf16(ah, bh0, acc[0], 0, 0, 0);
        acc[0] = __builtin_amdgcn_mfma_f32_32x32x16_bf16(ah, bl0, acc[0], 0, 0, 0);
        acc[0] = __builtin_amdgcn_mfma_f32_32x32x16_bf16(al, bh0, acc[0], 0, 0, 0);
        acc[1] = __builtin_amdgcn_mfma_f32_32x32x16_bf16(ah, bh1, acc[1], 0, 0, 0);
        acc[1] = __builtin_amdgcn_mfma_f32_32x32x16_bf16(ah, bl1, acc[1], 0, 0, 0);
        acc[1] = __builtin_amdgcn_mfma_f32_32x32x16_bf16(al, bh1, acc[1], 0, 0, 0);
        ah = nah; al = nal; bh0 = nbh0; bl0 = nbl0; bh1 = nbh1; bl1 = nbl1;
    }
    __syncthreads();  // params visible (only barrier in kernel body)

    // ---- col side (per wave: 64 cols x its 32 rows) ----
    // C/D layout [m74/m101]: col=lane&31, row=(reg&3)+8*(reg>>2)+4*(lane>>5)
    float cd2[2], cit2[2], cbloc[2], cg[2] = {}, cw[2] = {};
    for (int u = 0; u < 2; u++) {
        int clc = u * 32 + cl;
        cd2[u] = cDiag[clc];
        cit2[u] = cITau[clc];
        float m = -INFINITY;
        for (int reg = 0; reg < 16; reg++) m = fmaxf(m, acc[u][reg]);
        m = fmaxf(m, __shfl_xor(m, 32));
        cbloc[u] = (m - cd2[u]) * cit2[u];
    }
    for (int u = 0; u < 2; u++) {
        int gc = bn + u * 32 + cl;
        for (int reg = 0; reg < 16; reg++) {
            int gr = bm + wv * 32 + (reg & 3) + 4 * h + 8 * (reg >> 2);
            float v = acc[u][reg];
            bool off = gr != gc;
            float dvT = v - cd2[u];
            float eT = off ? __expf(dvT * cit2[u] - cbloc[u]) : 0.f;
            cg[u] += eT;
            cw[u] += eT * dvT;
        }
    }
    int stripeC = blockIdx.y * 4 + wv;
    for (int u = 0; u < 2; u++) {
        cg[u] += __shfl_xor(cg[u], 32);
        cw[u] += __shfl_xor(cw[u], 32);
        if (h == 0) {
            size_t o = (size_t)stripeC * BB + bn + u * 32 + cl;
            pmC[o] = cbloc[u];
            pgC[o] = cg[u];
            pwC[o] = cw[u];
        }
    }

    // ---- row side: per quad q (rows wv*32 + 8q + 4h + j) ----
    int stripeR = blockIdx.x;
    for (int q = 0; q < 4; q++) {
        float rd4[4], rit4[4], bloc[4], rg[4] = {}, rw[4] = {};
        for (int j = 0; j < 4; j++) {
            int rl = wv * 32 + 8 * q + 4 * h + j;
            rd4[j] = rDiag[rl];
            rit4[j] = rITau[rl];
        }
        for (int j = 0; j < 4; j++) {
            float m = fmaxf(acc[0][4 * q + j], acc[1][4 * q + j]);
            for (int mask = 1; mask <= 16; mask <<= 1)
                m = fmaxf(m, __shfl_xor(m, mask));
            bloc[j] = (m - rd4[j]) * rit4[j];
        }
        for (int u = 0; u < 2; u++) {
            int gc = bn + u * 32 + cl;
            for (int j = 0; j < 4; j++) {
                int gr = bm + wv * 32 + 8 * q + 4 * h + j;
                float v = acc[u][4 * q + j];
                bool off = gr != gc;
                float dvI = v - rd4[j];
                float eI = off ? __expf(dvI * rit4[j] - bloc[j]) : 0.f;
                rg[j] += eI;
                rw[j] += eI * dvI;
            }
        }
        for (int j = 0; j < 4; j++)
            for (int mask = 1; mask <= 16; mask <<= 1) {
                rg[j] += __shfl_xor(rg[j], mask);
                rw[j] += __shfl_xor(rw[j], mask);
            }
        if (cl == 0) {
            size_t o = (size_t)stripeR * BB + bm + wv * 32 + 8 * q + 4 * h;
            *(float4*)&pmR[o] = make_float4(bloc[0], bloc[1], bloc[2], bloc[3]);
            *(float4*)&pgR[o] = make_float4(rg[0], rg[1], rg[2], rg[3]);
            *(float4*)&pwR[o] = make_float4(rw[0], rw[1], rw[2], rw[3]);
        }
    }
}

// acc layout: [0]=lossI [1]=lossT [2..101]=gradI [102..201]=cntI
//             [202..301]=gradT [302..401]=cntT  [408]=completion counter(int)
// ---------------- 3) finalize both sides + last-block p-update --------------
__global__ void __launch_bounds__(256) fin_kernel(
        const float* __restrict__ pmR, const float* __restrict__ pgR,
        const float* __restrict__ pwR, const float* __restrict__ pmC,
        const float* __restrict__ pgC, const float* __restrict__ pwC,
        const float* __restrict__ sI, const float* __restrict__ bI,
        const float* __restrict__ tausI, const int* __restrict__ gInfI,
        const float* __restrict__ pI,
        const float* __restrict__ sT, const float* __restrict__ bT,
        const float* __restrict__ tausT, const int* __restrict__ gInfT,
        const float* __restrict__ pT,
        const int* __restrict__ ids, float* __restrict__ acc,
        const float* __restrict__ zI, const float* __restrict__ zT,
        float* __restrict__ out) {
    __shared__ float lds[8];
    __shared__ float binF[GG], binC[GG];
    __shared__ int lastFlag;
    if (threadIdx.x < GG) { binF[threadIdx.x] = 0.f; binC[threadIdx.x] = 0.f; }
    __syncthreads();
    int side = blockIdx.x >> 4;
    int i = (blockIdx.x & 15) * 256 + threadIdx.x;
    int ns = side ? NSC : NSR;
    const float* pm = side ? pmC : pmR;
    const float* pg = side ? pgC : pgR;
    const float* pw = side ? pwC : pwR;
    const float* sS = side ? sT : sI;
    const float* bS = side ? bT : bI;
    const float* taus = side ? tausT : tausI;
    const int* ginfo = side ? gInfT : gInfI;
    const float* pP = side ? pT : pI;

    int id = ids[i];
    float oldb = bS[id];
    float m = -INFINITY;
    for (int s = 0; s < ns; s++) m = fmaxf(m, pm[(size_t)s * BB + i]);
    float bfin = fmaxf(m, oldb);
    float g = 0.f, wsum = 0.f;
    for (int s = 0; s < ns; s++) {
        float f = __expf(pm[(size_t)s * BB + i] - bfin);
        g += pg[(size_t)s * BB + i] * f;
        wsum += pw[(size_t)s * BB + i] * f;
    }
    float tau = taus[id];
    float snew = (1.f - GAMMA_C) * sS[id] * expf(oldb - bfin) + GAMMA_C * g;
    float sc = fmaxf(snew, EPS_C);
    int gid = ginfo[id];
    float gw = (float)GG * pP[gid];
    float loss = gw * wsum / sc;
    float F = tau * (logf(sc) + bfin + RHO_C);
    atomicAdd(&binF[gid], F);
    atomicAdd(&binC[gid], 1.0f);
    float lsum = blockReduceSum(loss, lds);
    if (threadIdx.x == 0) atomicAdd(&acc[side], lsum);
    __syncthreads();
    if (threadIdx.x < GG) {
        atomicAdd(&acc[2 + side * 200 + threadIdx.x], binF[threadIdx.x]);
        atomicAdd(&acc[102 + side * 200 + threadIdx.x], binC[threadIdx.x]);
    }

    // ---- completion counter: last of 32 blocks runs the p-update phase ----
    __threadfence();
    if (threadIdx.x == 0) {
        int old = atomicAdd((int*)&acc[408], 1);
        lastFlag = (old == 31);
    }
    __syncthreads();
    if (!lastFlag) return;

    int gg = threadIdx.x;
    float npI = 0.f, npT = 0.f;
    if (gg < GG) {
        float cI = __hip_atomic_load(&acc[102 + gg], __ATOMIC_RELAXED, __HIP_MEMORY_SCOPE_AGENT);
        float fI = __hip_atomic_load(&acc[2 + gg], __ATOMIC_RELAXED, __HIP_MEMORY_SCOPE_AGENT);
        float gpI = fI / fmaxf(cI, 1.f);
        float zi = (1.f - GAMMA_C) * zI[gg] + GAMMA_C * gpI;
        float ghpI = -logf(pI[gg] + EPS_C) - 1.f;
        float ti = fminf(fmaxf(zi + ghpI, -5.f), 5.f);
        npI = pI[gg] * expf(0.02f * ti);

        float cT = __hip_atomic_load(&acc[302 + gg], __ATOMIC_RELAXED, __HIP_MEMORY_SCOPE_AGENT);
        float fT = __hip_atomic_load(&acc[202 + gg], __ATOMIC_RELAXED, __HIP_MEMORY_SCOPE_AGENT);
        float gpT = fT / fmaxf(cT, 1.f);
        float zt = (1.f - GAMMA_C) * zT[gg] + GAMMA_C * gpT;
        float ghpT = -logf(pT[gg] + EPS_C) - 1.f;
        float tt = fminf(fmaxf(zt + ghpT, -5.f), 5.f);
        npT = pT[gg] * expf(0.02f * tt);
    }
    float sumI = blockReduceSum(npI, lds);
    float sumT = blockReduceSum(npT, lds);
    if (gg < GG) {
        out[1 + gg] = npI / sumI;
        out[101 + gg] = npT / sumT;
    }
    if (gg == 0) {
        float lI = __hip_atomic_load(&acc[0], __ATOMIC_RELAXED, __HIP_MEMORY_SCOPE_AGENT);
        float lT = __hip_atomic_load(&acc[1], __ATOMIC_RELAXED, __HIP_MEMORY_SCOPE_AGENT);
        out[0] = ALPHA_C * (lI / (float)BB) + (1.f - ALPHA_C) * (lT / (float)BB);
    }
}

extern "C" void kernel_launch(void* const* d_in, const int* in_sizes, int n_in,
                              void* d_out, int out_size, void* d_ws, size_t ws_size,
                              hipStream_t stream) {
    const float* zis   = (const float*)d_in[0];
    const float* zjs   = (const float*)d_in[1];
    const float* s_I   = (const float*)d_in[2];
    const float* s_T   = (const float*)d_in[3];
    const float* b_I   = (const float*)d_in[4];
    const float* b_T   = (const float*)d_in[5];
    const float* z_I   = (const float*)d_in[6];
    const float* z_T   = (const float*)d_in[7];
    const float* p_I   = (const float*)d_in[8];
    const float* p_T   = (const float*)d_in[9];
    const float* tausI = (const float*)d_in[10];
    const float* tausT = (const float*)d_in[11];
    const int*   ids   = (const int*)d_in[12];
    const int*   gInfI = (const int*)d_in[13];
    const int*   gInfT = (const int*)d_in[14];
    float* out = (float*)d_out;

    char* ws = (char*)d_ws;
    ushort* zhi = (ushort*)ws;                         // BB*DD u16 each
    ushort* zlo = zhi + (size_t)BB * DD;
    ushort* whi = zlo + (size_t)BB * DD;
    ushort* wlo = whi + (size_t)BB * DD;
    float* acc  = (float*)(wlo + (size_t)BB * DD);     // 512
    float* diag = acc + 512;                           // BB
    float* pmR  = diag + BB;                           // NSR*BB each
    float* pgR  = pmR + (size_t)NSR * BB;
    float* pwR  = pgR + (size_t)NSR * BB;
    float* pmC  = pwR + (size_t)NSR * BB;              // NSC*BB each
    float* pgC  = pmC + (size_t)NSC * BB;
    float* pwC  = pgC + (size_t)NSC * BB;

    norm_kernel<<<128, 256, 0, stream>>>(zis, zjs, zhi, zlo, whi, wlo, diag, acc);
    fused_tile<<<dim3(64, 32), 256, 0, stream>>>(zhi, zlo, whi, wlo, diag,
            tausI, tausT, ids, pmR, pgR, pwR, pmC, pgC, pwC);
    fin_kernel<<<32, 256, 0, stream>>>(pmR, pgR, pwR, pmC, pgC, pwC,
            s_I, b_I, tausI, gInfI, p_I, s_T, b_T, tausT, gInfT, p_T, ids, acc,
            z_I, z_T, out);
}

// Round 11
// 279.504 us; speedup vs baseline: 1.1631x; 1.1631x over previous
//
#include <hip/hip_runtime.h>
#include <hip/hip_bf16.h>
#include <math.h>

#define BB 4096
#define DD 256
#define GG 100
#define GAMMA_C 0.8f
#define RHO_C 8.0f
#define ALPHA_C 0.5f
#define EPS_C 1e-14f
#define NSR 64    // row stripes (64-col tiles)
#define NSC 32    // col stripes (one per 128-row block; waves pre-combined)

typedef __bf16 bf16x8 __attribute__((ext_vector_type(8)));
typedef float f32x16 __attribute__((ext_vector_type(16)));

// 32-row fragment-swizzled layout for mfma_32x32x16: element (r,k) ->
//   row_blk=r>>5 (stride 8192), step=k>>4 (stride 512),
//   lane=((k>>3)&1)*32 + (r&31) (stride 8), pos=k&7. Packs exactly.
__device__ inline int swzLoc(int r31, int k) {   // offset within 8192-elem block
    return ((k >> 4) << 9) | (((((k >> 3) & 1) << 5) | r31) << 3) | (k & 7);
}

__device__ inline float blockReduceSum(float v, float* lds) {
    for (int o = 32; o > 0; o >>= 1) v += __shfl_down(v, o);
    int lane = threadIdx.x & 63, wid = threadIdx.x >> 6;
    if (lane == 0) lds[wid] = v;
    __syncthreads();
    if (threadIdx.x == 0) {
        float r = lds[0];
        int nw = blockDim.x >> 6;
        for (int w = 1; w < nw; w++) r += lds[w];
        lds[0] = r;
    }
    __syncthreads();
    float r = lds[0];
    __syncthreads();
    return r;
}

// ---------------- 1) normalize + hi/lo split, LDS-staged swizzled stores ----
__global__ void __launch_bounds__(256) norm_kernel(const float* __restrict__ zis,
                            const float* __restrict__ zjs,
                            ushort* __restrict__ zhi, ushort* __restrict__ zlo,
                            ushort* __restrict__ whi, ushort* __restrict__ wlo,
                            float* __restrict__ diag, float* __restrict__ acc) {
    __shared__ ushort st[4][8192];   // 64 KB staging (zhi,zlo,whi,wlo)
    int rb = blockIdx.x;             // 0..127
    int wv = threadIdx.x >> 6, lane = threadIdx.x & 63;
    if (rb == 0) { acc[threadIdx.x] = 0.f; acc[threadIdx.x + 256] = 0.f; }
    for (int rr = 0; rr < 8; rr++) {
        int r = rb * 32 + wv * 8 + rr;
        float4 zv = *(const float4*)&zis[r * DD + lane * 4];
        float4 wv4 = *(const float4*)&zjs[r * DD + lane * 4];
        float sz = zv.x * zv.x + zv.y * zv.y + zv.z * zv.z + zv.w * zv.w;
        float sw = wv4.x * wv4.x + wv4.y * wv4.y + wv4.z * wv4.z + wv4.w * wv4.w;
        float dt = zv.x * wv4.x + zv.y * wv4.y + zv.z * wv4.z + zv.w * wv4.w;
        for (int mask = 1; mask <= 32; mask <<= 1) {
            sz += __shfl_xor(sz, mask);
            sw += __shfl_xor(sw, mask);
            dt += __shfl_xor(dt, mask);
        }
        float iz = 1.0f / fmaxf(sqrtf(sz), 1e-12f);
        float iw = 1.0f / fmaxf(sqrtf(sw), 1e-12f);
        if (lane == 0) diag[r] = dt * iz * iw;
        float nz[4] = {zv.x * iz, zv.y * iz, zv.z * iz, zv.w * iz};
        float nw[4] = {wv4.x * iw, wv4.y * iw, wv4.z * iw, wv4.w * iw};
        int r31 = wv * 8 + rr;
        for (int e = 0; e < 4; e++) {
            int k = lane * 4 + e;
            int li = swzLoc(r31, k);
            __hip_bfloat16 hz = __float2bfloat16(nz[e]);
            __hip_bfloat16 lz = __float2bfloat16(nz[e] - __bfloat162float(hz));
            __hip_bfloat16 hw = __float2bfloat16(nw[e]);
            __hip_bfloat16 lw = __float2bfloat16(nw[e] - __bfloat162float(hw));
            st[0][li] = *(ushort*)&hz;
            st[1][li] = *(ushort*)&lz;
            st[2][li] = *(ushort*)&hw;
            st[3][li] = *(ushort*)&lw;
        }
    }
    __syncthreads();
    size_t base = (size_t)rb * 8192;
    ushort* dsts[4] = {zhi + base, zlo + base, whi + base, wlo + base};
    for (int a = 0; a < 4; a++) {
        uint4* d = (uint4*)dsts[a];
        const uint4* s = (const uint4*)st[a];
        for (int it = 0; it < 4; it++) {
            int idx = it * 256 + threadIdx.x;
            d[idx] = s[idx];
        }
    }
}

// ---------------- 2) fused tile: 128x64 block, 32x32x16 MFMA, prefetched ----
__global__ void __launch_bounds__(256, 4) fused_tile(const ushort* __restrict__ Ahi,
        const ushort* __restrict__ Alo, const ushort* __restrict__ Bhi,
        const ushort* __restrict__ Blo, const float* __restrict__ diag,
        const float* __restrict__ tausI, const float* __restrict__ tausT,
        const int* __restrict__ ids,
        float* __restrict__ pmR, float* __restrict__ pgR, float* __restrict__ pwR,
        float* __restrict__ pmC, float* __restrict__ pgC, float* __restrict__ pwC) {
    __shared__ float rDiag[128], rITau[128];
    __shared__ float cDiag[64], cITau[64];
    __shared__ float cmS[4][64], cgS[4][64], cwS[4][64];  // wave col partials

    int lane = threadIdx.x & 63;
    int wv = threadIdx.x >> 6;
    int bm = blockIdx.y * 128, bn = blockIdx.x * 64;
    int h = lane >> 5, cl = lane & 31;

    if (threadIdx.x < 128) {
        int r = bm + threadIdx.x;
        rDiag[threadIdx.x] = diag[r];
        rITau[threadIdx.x] = 1.0f / tausI[ids[r]];
    } else if (threadIdx.x < 192) {
        int c = bn + threadIdx.x - 128;
        cDiag[threadIdx.x - 128] = diag[c];
        cITau[threadIdx.x - 128] = 1.0f / tausT[ids[c]];
    }

    int aBase = (blockIdx.y * 4 + wv) * 8192;
    int b0 = (blockIdx.x * 2) * 8192;
    int b1 = b0 + 8192;
    int lofs = lane * 8;

    f32x16 acc[2] = {};
    bf16x8 ah, al, bh0, bl0, bh1, bl1;
    ah  = *(const bf16x8*)&Ahi[aBase + lofs];
    al  = *(const bf16x8*)&Alo[aBase + lofs];
    bh0 = *(const bf16x8*)&Bhi[b0 + lofs];
    bl0 = *(const bf16x8*)&Blo[b0 + lofs];
    bh1 = *(const bf16x8*)&Bhi[b1 + lofs];
    bl1 = *(const bf16x8*)&Blo[b1 + lofs];
#pragma unroll
    for (int s = 0; s < 16; s++) {
        bf16x8 nah, nal, nbh0, nbl0, nbh1, nbl1;
        if (s < 15) {
            int so = (s + 1) * 512 + lofs;
            nah  = *(const bf16x8*)&Ahi[aBase + so];
            nal  = *(const bf16x8*)&Alo[aBase + so];
            nbh0 = *(const bf16x8*)&Bhi[b0 + so];
            nbl0 = *(const bf16x8*)&Blo[b0 + so];
            nbh1 = *(const bf16x8*)&Bhi[b1 + so];
            nbl1 = *(const bf16x8*)&Blo[b1 + so];
        }
        acc[0] = __builtin_amdgcn_mfma_f32_32x32x16_bf16(ah, bh0, acc[0], 0, 0, 0);
        acc[0] = __builtin_amdgcn_mfma_f32_32x32x16_bf16(ah, bl0, acc[0], 0, 0, 0);
        acc[0] = __builtin_amdgcn_mfma_f32_32x32x16_bf16(al, bh0, acc[0], 0, 0, 0);
        acc[1] = __builtin_amdgcn_mfma_f32_32x32x16_bf16(ah, bh1, acc[1], 0, 0, 0);
        acc[1] = __builtin_amdgcn_mfma_f32_32x32x16_bf16(ah, bl1, acc[1], 0, 0, 0);
        acc[1] = __builtin_amdgcn_mfma_f32_32x32x16_bf16(al, bh1, acc[1], 0, 0, 0);
        ah = nah; al = nal; bh0 = nbh0; bl0 = nbl0; bh1 = nbh1; bl1 = nbl1;
    }
    __syncthreads();  // params visible

    // ---- col side (per wave: 64 cols x its 32 rows) ----
    // C/D layout [m74/m101]: col=lane&31, row=(reg&3)+8*(reg>>2)+4*(lane>>5)
    float cd2[2], cit2[2], cbloc[2], cg[2] = {}, cw[2] = {};
    for (int u = 0; u < 2; u++) {
        int clc = u * 32 + cl;
        cd2[u] = cDiag[clc];
        cit2[u] = cITau[clc];
        float m = -INFINITY;
        for (int reg = 0; reg < 16; reg++) m = fmaxf(m, acc[u][reg]);
        m = fmaxf(m, __shfl_xor(m, 32));
        cbloc[u] = (m - cd2[u]) * cit2[u];
    }
    for (int u = 0; u < 2; u++) {
        int gc = bn + u * 32 + cl;
        for (int reg = 0; reg < 16; reg++) {
            int gr = bm + wv * 32 + (reg & 3) + 4 * h + 8 * (reg >> 2);
            float v = acc[u][reg];
            bool off = gr != gc;
            float dvT = v - cd2[u];
            float eT = off ? __expf(dvT * cit2[u] - cbloc[u]) : 0.f;
            cg[u] += eT;
            cw[u] += eT * dvT;
        }
    }
    for (int u = 0; u < 2; u++) {
        cg[u] += __shfl_xor(cg[u], 32);
        cw[u] += __shfl_xor(cw[u], 32);
        if (h == 0) {
            cmS[wv][u * 32 + cl] = cbloc[u];
            cgS[wv][u * 32 + cl] = cg[u];
            cwS[wv][u * 32 + cl] = cw[u];
        }
    }
    __syncthreads();
    // flash-combine 4 waves -> 1 col stripe per block (NSC=32)
    if (threadIdx.x < 64) {
        int c = threadIdx.x;
        float m = fmaxf(fmaxf(cmS[0][c], cmS[1][c]), fmaxf(cmS[2][c], cmS[3][c]));
        float g = 0.f, w = 0.f;
        for (int wq = 0; wq < 4; wq++) {
            float f = __expf(cmS[wq][c] - m);
            g += cgS[wq][c] * f;
            w += cwS[wq][c] * f;
        }
        size_t o = (size_t)blockIdx.y * BB + bn + c;
        pmC[o] = m;
        pgC[o] = g;
        pwC[o] = w;
    }

    // ---- row side: per quad q (rows wv*32 + 8q + 4h + j) ----
    int stripeR = blockIdx.x;
    for (int q = 0; q < 4; q++) {
        float rd4[4], rit4[4], bloc[4], rg[4] = {}, rw[4] = {};
        for (int j = 0; j < 4; j++) {
            int rl = wv * 32 + 8 * q + 4 * h + j;
            rd4[j] = rDiag[rl];
            rit4[j] = rITau[rl];
        }
        for (int j = 0; j < 4; j++) {
            float m = fmaxf(acc[0][4 * q + j], acc[1][4 * q + j]);
            for (int mask = 1; mask <= 16; mask <<= 1)
                m = fmaxf(m, __shfl_xor(m, mask));
            bloc[j] = (m - rd4[j]) * rit4[j];
        }
        for (int u = 0; u < 2; u++) {
            int gc = bn + u * 32 + cl;
            for (int j = 0; j < 4; j++) {
                int gr = bm + wv * 32 + 8 * q + 4 * h + j;
                float v = acc[u][4 * q + j];
                bool off = gr != gc;
                float dvI = v - rd4[j];
                float eI = off ? __expf(dvI * rit4[j] - bloc[j]) : 0.f;
                rg[j] += eI;
                rw[j] += eI * dvI;
            }
        }
        for (int j = 0; j < 4; j++)
            for (int mask = 1; mask <= 16; mask <<= 1) {
                rg[j] += __shfl_xor(rg[j], mask);
                rw[j] += __shfl_xor(rw[j], mask);
            }
        if (cl == 0) {
            size_t o = (size_t)stripeR * BB + bm + wv * 32 + 8 * q + 4 * h;
            *(float4*)&pmR[o] = make_float4(bloc[0], bloc[1], bloc[2], bloc[3]);
            *(float4*)&pgR[o] = make_float4(rg[0], rg[1], rg[2], rg[3]);
            *(float4*)&pwR[o] = make_float4(rw[0], rw[1], rw[2], rw[3]);
        }
    }
}

// acc layout: [0]=lossI [1]=lossT [2..101]=gradI [102..201]=cntI
//             [202..301]=gradT [302..401]=cntT  [408]=completion counter(int)
// ---------------- 3) finalize: 128 blocks (2 sides x 64 chunks of 64 i) -----
// 256 threads = 64 i x 4 stripe-groups; online flash reduction per thread,
// LDS-combine across groups. Fixes R10's 8K-thread latency bind (65 us).
__global__ void __launch_bounds__(256) fin_kernel(
        const float* __restrict__ pmR, const float* __restrict__ pgR,
        const float* __restrict__ pwR, const float* __restrict__ pmC,
        const float* __restrict__ pgC, const float* __restrict__ pwC,
        const float* __restrict__ sI, const float* __restrict__ bI,
        const float* __restrict__ tausI, const int* __restrict__ gInfI,
        const float* __restrict__ pI,
        const float* __restrict__ sT, const float* __restrict__ bT,
        const float* __restrict__ tausT, const int* __restrict__ gInfT,
        const float* __restrict__ pT,
        const int* __restrict__ ids, float* __restrict__ acc,
        const float* __restrict__ zI, const float* __restrict__ zT,
        float* __restrict__ out) {
    __shared__ float lds[8];
    __shared__ float binF[GG], binC[GG];
    __shared__ float mS[4][64], gS[4][64], wS[4][64];
    __shared__ int lastFlag;
    if (threadIdx.x < GG) { binF[threadIdx.x] = 0.f; binC[threadIdx.x] = 0.f; }
    int side = blockIdx.x >> 6;
    int chunk = blockIdx.x & 63;
    int il = threadIdx.x & 63;
    int sg = threadIdx.x >> 6;
    int i = chunk * 64 + il;
    int ns = side ? NSC : NSR;
    const float* pm = side ? pmC : pmR;
    const float* pg = side ? pgC : pgR;
    const float* pw = side ? pwC : pwR;
    const float* sS = side ? sT : sI;
    const float* bS = side ? bT : bI;
    const float* taus = side ? tausT : tausI;
    const int* ginfo = side ? gInfT : gInfI;
    const float* pP = side ? pT : pI;

    // online flash over this group's stripes
    float m = -INFINITY, g = 0.f, w = 0.f;
    for (int s = sg; s < ns; s += 4) {
        float pms = pm[(size_t)s * BB + i];
        float pgs = pg[(size_t)s * BB + i];
        float pws = pw[(size_t)s * BB + i];
        float mn = fmaxf(m, pms);
        float fo = __expf(m - mn);
        float fs = __expf(pms - mn);
        g = g * fo + pgs * fs;
        w = w * fo + pws * fs;
        m = mn;
    }
    mS[sg][il] = m;
    gS[sg][il] = g;
    wS[sg][il] = w;
    __syncthreads();

    float loss = 0.f;
    if (sg == 0) {
        int id = ids[i];
        float oldb = bS[id];
        float mm = fmaxf(fmaxf(mS[0][il], mS[1][il]), fmaxf(mS[2][il], mS[3][il]));
        float bfin = fmaxf(mm, oldb);
        float gg2 = 0.f, ww2 = 0.f;
        for (int q = 0; q < 4; q++) {
            float f = __expf(mS[q][il] - bfin);
            gg2 += gS[q][il] * f;
            ww2 += wS[q][il] * f;
        }
        float tau = taus[id];
        float snew = (1.f - GAMMA_C) * sS[id] * expf(oldb - bfin) + GAMMA_C * gg2;
        float sc = fmaxf(snew, EPS_C);
        int gid = ginfo[id];
        float gw = (float)GG * pP[gid];
        loss = gw * ww2 / sc;
        float F = tau * (logf(sc) + bfin + RHO_C);
        atomicAdd(&binF[gid], F);
        atomicAdd(&binC[gid], 1.0f);
    }
    float lsum = blockReduceSum(loss, lds);
    if (threadIdx.x == 0) atomicAdd(&acc[side], lsum);
    __syncthreads();
    if (threadIdx.x < GG) {
        atomicAdd(&acc[2 + side * 200 + threadIdx.x], binF[threadIdx.x]);
        atomicAdd(&acc[102 + side * 200 + threadIdx.x], binC[threadIdx.x]);
    }

    // ---- completion counter: last of 128 blocks runs the p-update phase ----
    __threadfence();
    if (threadIdx.x == 0) {
        int old = atomicAdd((int*)&acc[408], 1);
        lastFlag = (old == 127);
    }
    __syncthreads();
    if (!lastFlag) return;

    int gg = threadIdx.x;
    float npI = 0.f, npT = 0.f;
    if (gg < GG) {
        float cI = __hip_atomic_load(&acc[102 + gg], __ATOMIC_RELAXED, __HIP_MEMORY_SCOPE_AGENT);
        float fI = __hip_atomic_load(&acc[2 + gg], __ATOMIC_RELAXED, __HIP_MEMORY_SCOPE_AGENT);
        float gpI = fI / fmaxf(cI, 1.f);
        float zi = (1.f - GAMMA_C) * zI[gg] + GAMMA_C * gpI;
        float ghpI = -logf(pI[gg] + EPS_C) - 1.f;
        float ti = fminf(fmaxf(zi + ghpI, -5.f), 5.f);
        npI = pI[gg] * expf(0.02f * ti);

        float cT = __hip_atomic_load(&acc[302 + gg], __ATOMIC_RELAXED, __HIP_MEMORY_SCOPE_AGENT);
        float fT = __hip_atomic_load(&acc[202 + gg], __ATOMIC_RELAXED, __HIP_MEMORY_SCOPE_AGENT);
        float gpT = fT / fmaxf(cT, 1.f);
        float zt = (1.f - GAMMA_C) * zT[gg] + GAMMA_C * gpT;
        float ghpT = -logf(pT[gg] + EPS_C) - 1.f;
        float tt = fminf(fmaxf(zt + ghpT, -5.f), 5.f);
        npT = pT[gg] * expf(0.02f * tt);
    }
    float sumI = blockReduceSum(npI, lds);
    float sumT = blockReduceSum(npT, lds);
    if (gg < GG) {
        out[1 + gg] = npI / sumI;
        out[101 + gg] = npT / sumT;
    }
    if (gg == 0) {
        float lI = __hip_atomic_load(&acc[0], __ATOMIC_RELAXED, __HIP_MEMORY_SCOPE_AGENT);
        float lT = __hip_atomic_load(&acc[1], __ATOMIC_RELAXED, __HIP_MEMORY_SCOPE_AGENT);
        out[0] = ALPHA_C * (lI / (float)BB) + (1.f - ALPHA_C) * (lT / (float)BB);
    }
}

extern "C" void kernel_launch(void* const* d_in, const int* in_sizes, int n_in,
                              void* d_out, int out_size, void* d_ws, size_t ws_size,
                              hipStream_t stream) {
    const float* zis   = (const float*)d_in[0];
    const float* zjs   = (const float*)d_in[1];
    const float* s_I   = (const float*)d_in[2];
    const float* s_T   = (const float*)d_in[3];
    const float* b_I   = (const float*)d_in[4];
    const float* b_T   = (const float*)d_in[5];
    const float* z_I   = (const float*)d_in[6];
    const float* z_T   = (const float*)d_in[7];
    const float* p_I   = (const float*)d_in[8];
    const float* p_T   = (const float*)d_in[9];
    const float* tausI = (const float*)d_in[10];
    const float* tausT = (const float*)d_in[11];
    const int*   ids   = (const int*)d_in[12];
    const int*   gInfI = (const int*)d_in[13];
    const int*   gInfT = (const int*)d_in[14];
    float* out = (float*)d_out;

    char* ws = (char*)d_ws;
    ushort* zhi = (ushort*)ws;                         // BB*DD u16 each
    ushort* zlo = zhi + (size_t)BB * DD;
    ushort* whi = zlo + (size_t)BB * DD;
    ushort* wlo = whi + (size_t)BB * DD;
    float* acc  = (float*)(wlo + (size_t)BB * DD);     // 512
    float* diag = acc + 512;                           // BB
    float* pmR  = diag + BB;                           // NSR*BB each
    float* pgR  = pmR + (size_t)NSR * BB;
    float* pwR  = pgR + (size_t)NSR * BB;
    float* pmC  = pwR + (size_t)NSR * BB;              // NSC*BB each
    float* pgC  = pmC + (size_t)NSC * BB;
    float* pwC  = pgC + (size_t)NSC * BB;

    norm_kernel<<<128, 256, 0, stream>>>(zis, zjs, zhi, zlo, whi, wlo, diag, acc);
    fused_tile<<<dim3(64, 32), 256, 0, stream>>>(zhi, zlo, whi, wlo, diag,
            tausI, tausT, ids, pmR, pgR, pwR, pmC, pgC, pwC);
    fin_kernel<<<128, 256, 0, stream>>>(pmR, pgR, pwR, pmC, pgC, pwC,
            s_I, b_I, tausI, gInfI, p_I, s_T, b_T, tausT, gInfT, p_T, ids, acc,
            z_I, z_T, out);
}